// Round 10
// baseline (140.927 us; speedup 1.0000x reference)
//
#include <hip/hip_runtime.h>

// NetVLAD: N=16, C=1024, P=1024, K=32. Three dispatches.
// Harness note (R9 analysis): each timed iteration = 16 dispatches incl. TWO
// 256MiB workspace-poison fills (~84us immovable). Our kernels are the ~40us
// on top; this rev targets them via 16B loads + TLP + fewer barriers.
//  k_attn: fused logits+rnorm+softmax. grid 512 = (n, 32-p tile), block 256.
//     4 iters of 256-c chunks (4 barriers): every x load 16B (4 c-rows x 8 p
//     per thread), 4x8 register transpose -> dbuf LDS (xT only!), W fragments
//     read DIRECT from global (64KB, L2-hot). Epilogue: parallel softmax,
//     a' = a * rnorm bf16 (vlad needs no rnorm), asum partials.
//  k_vlad: grid 512 = (n, 32c), block 512 = 8 waves (2k x 2c x 2p halves),
//     fragment-direct MFMA from global; bf16 path feeds raw x to MFMA (no
//     cvt). p-half partials combined via LDS. Fused -asum*cent, ssq partials.
//  k_out: (n, k) intra+global norms, scaled write. (Verified, unchanged.)
// Runtime dtype detect (fp32 vs bf16) per block; fp32 accumulate throughout.
#define NB   16
#define CC   1024
#define PP   1024
#define KK   32
#define EPSF 1e-12f

typedef __attribute__((ext_vector_type(8))) short  bf16x8;
typedef __attribute__((ext_vector_type(8))) short  s16x8;
typedef __attribute__((ext_vector_type(4))) float  f32x4;
typedef __attribute__((ext_vector_type(8))) float  f32x8;

__device__ __forceinline__ float bf2f(unsigned short u) {
    union { unsigned int i; float f; } v; v.i = ((unsigned int)u) << 16; return v.f;
}
__device__ __forceinline__ unsigned short f2bf(float f) {
    union { float f; unsigned int i; } v; v.f = f;
    return (unsigned short)((v.i + 0x7fffu + ((v.i >> 16) & 1u)) >> 16);  // RNE
}

template <typename T> struct IO;
template <> struct IO<float> {
    static __device__ __forceinline__ float ld(const float* p) { return *p; }
    static __device__ __forceinline__ f32x8 ld8(const float* p) {   // 2 x 16B
        const f32x4 a = *(const f32x4*)p, b = *(const f32x4*)(p + 4);
        f32x8 r;
        r[0] = a[0]; r[1] = a[1]; r[2] = a[2]; r[3] = a[3];
        r[4] = b[0]; r[5] = b[1]; r[6] = b[2]; r[7] = b[3];
        return r;
    }
    static __device__ __forceinline__ bf16x8 frag8(const float* p) { // ->bf16
        const f32x4 a = *(const f32x4*)p, b = *(const f32x4*)(p + 4);
        bf16x8 r;
        r[0] = (short)f2bf(a[0]); r[1] = (short)f2bf(a[1]);
        r[2] = (short)f2bf(a[2]); r[3] = (short)f2bf(a[3]);
        r[4] = (short)f2bf(b[0]); r[5] = (short)f2bf(b[1]);
        r[6] = (short)f2bf(b[2]); r[7] = (short)f2bf(b[3]);
        return r;
    }
    static __device__ __forceinline__ void st4(float* p, f32x4 v) { *(f32x4*)p = v; }
};
template <> struct IO<unsigned short> {
    static __device__ __forceinline__ float ld(const unsigned short* p) { return bf2f(*p); }
    static __device__ __forceinline__ f32x8 ld8(const unsigned short* p) { // 1 x 16B
        const s16x8 u = *(const s16x8*)p;
        f32x8 r;
        #pragma unroll
        for (int j = 0; j < 8; ++j) r[j] = bf2f((unsigned short)u[j]);
        return r;
    }
    static __device__ __forceinline__ bf16x8 frag8(const unsigned short* p) {
        return *(const bf16x8*)p;                                    // raw 16B
    }
    static __device__ __forceinline__ void st4(unsigned short* p, f32x4 v) {
        ushort4 u;
        u.x = f2bf(v[0]); u.y = f2bf(v[1]); u.z = f2bf(v[2]); u.w = f2bf(v[3]);
        *(ushort4*)p = u;
    }
};

// Barrier WITHOUT vmcnt drain: waves wait only their own LDS ops; prefetch
// global loads stay in flight across the barrier.
__device__ __forceinline__ void wg_sync_fast() {
    asm volatile("s_waitcnt lgkmcnt(0)" ::: "memory");
    __builtin_amdgcn_s_barrier();
    asm volatile("" ::: "memory");
}

// ---------------------------------------------------------------------------
// K1: fused attn. grid 512 = (n<<5 | ptile), block 256 = 4 waves.
// ---------------------------------------------------------------------------
struct __align__(16) AttnSmem {
    union {
        unsigned short xT[2][32][264];      // main loop: [buf][p][c] 528B rows
        struct {                            // epilogue (~15 KB)
            float red[64][32];              // sumsq [c-quad][p]
            float lg[32][33];               // logits [p][k]
            float rn[32];
            float asq[4][32];               // per-wave asum partials [wv][k]
            unsigned short at[32][33];      // a' bf16 [k][p]
        } e;
    } u;
};

template <typename T>
__device__ __forceinline__ void attn_body(const T* __restrict__ x,
                                          const T* __restrict__ w,
                                          AttnSmem& sm,
                                          unsigned short* __restrict__ attn_g,
                                          float* __restrict__ asum_p) {
    const int b = blockIdx.x, t = threadIdx.x;
    const int n = b >> 5, pt = b & 31, p0 = pt * 32;
    const int lane = t & 63, wv = t >> 6;
    const int quad = lane >> 4, l15 = lane & 15;
    const int khalf = wv >> 1, phalf = wv & 1;
    const int ci = t >> 2;          // c-quad 0..63 (4 rows of the 256-c chunk)
    const int pj = t & 3;           // p-octet 0..3 (8 p)
    const size_t xb = (size_t)n * CC * PP + p0 + 8 * pj;
    const T* wrow = w + (size_t)(khalf * 16 + l15) * CC;   // W fragment row

    float ss[8] = {0.f, 0.f, 0.f, 0.f, 0.f, 0.f, 0.f, 0.f};
    f32x4 acc = {0.f, 0.f, 0.f, 0.f};

    // depth-1 prefetch: 4 rows x 8 p, all-16B loads
    f32x8 xr[4];
    #pragma unroll
    for (int r = 0; r < 4; ++r)
        xr[r] = IO<T>::ld8(&x[xb + (size_t)(4 * ci + r) * PP]);

    #pragma unroll
    for (int it = 0; it < 4; ++it) {
        const int buf = it & 1;
        // 4x8 register transpose -> xT, sumsq
        #pragma unroll
        for (int jj = 0; jj < 8; ++jj) {
            ss[jj] += xr[0][jj] * xr[0][jj] + xr[1][jj] * xr[1][jj]
                    + xr[2][jj] * xr[2][jj] + xr[3][jj] * xr[3][jj];
            ushort4 u;
            u.x = f2bf(xr[0][jj]); u.y = f2bf(xr[1][jj]);
            u.z = f2bf(xr[2][jj]); u.w = f2bf(xr[3][jj]);
            *(ushort4*)&sm.u.xT[buf][8 * pj + jj][4 * ci] = u;
        }
        // issue next-chunk loads; they stay in flight across the barrier
        if (it < 3) {
            const int c0 = (it + 1) * 256;
            #pragma unroll
            for (int r = 0; r < 4; ++r)
                xr[r] = IO<T>::ld8(&x[xb + (size_t)(c0 + 4 * ci + r) * PP]);
        }
        wg_sync_fast();
        // MFMA: A = W k-rows (global-direct, L2-hot), B = xT p-rows.
        // D row m -> k = khalf*16+quad*4+reg, col n -> p = phalf*16+l15.
        #pragma unroll
        for (int ks = 0; ks < 8; ++ks) {
            const bf16x8 av = IO<T>::frag8(&wrow[it * 256 + ks * 32 + quad * 8]);
            const bf16x8 bv = *(const bf16x8*)&sm.u.xT[buf][phalf * 16 + l15][ks * 32 + quad * 8];
            acc = __builtin_amdgcn_mfma_f32_16x16x32_bf16(av, bv, acc, 0, 0, 0);
        }
    }
    __syncthreads();   // main-loop LDS dead beyond here; union reuse is safe

    // sumsq partials + logits into epilogue arrays
    #pragma unroll
    for (int jj = 0; jj < 8; ++jj) sm.u.e.red[ci][8 * pj + jj] = ss[jj];
    #pragma unroll
    for (int reg = 0; reg < 4; ++reg)
        sm.u.e.lg[phalf * 16 + l15][khalf * 16 + quad * 4 + reg] = acc[reg];
    __syncthreads();
    if (t < 32) {
        float s = 0.f;
        #pragma unroll
        for (int g = 0; g < 64; ++g) s += sm.u.e.red[g][t];
        sm.u.e.rn[t] = 1.0f / fmaxf(sqrtf(s), EPSF);
    }
    __syncthreads();
    {   // parallel softmax: p = t>>3, 4 k per thread, 8-lane k-reduction
        const int p = t >> 3, kg = (t & 7) * 4;
        const float rr = sm.u.e.rn[p];
        float l[4];
        #pragma unroll
        for (int q = 0; q < 4; ++q) l[q] = sm.u.e.lg[p][kg + q] * rr;
        float mx = fmaxf(fmaxf(l[0], l[1]), fmaxf(l[2], l[3]));
        mx = fmaxf(mx, __shfl_xor(mx, 1, 64));
        mx = fmaxf(mx, __shfl_xor(mx, 2, 64));
        mx = fmaxf(mx, __shfl_xor(mx, 4, 64));
        float e[4], sum = 0.f;
        #pragma unroll
        for (int q = 0; q < 4; ++q) { e[q] = expf(l[q] - mx); sum += e[q]; }
        sum += __shfl_xor(sum, 1, 64);
        sum += __shfl_xor(sum, 2, 64);
        sum += __shfl_xor(sum, 4, 64);
        const float inv = 1.0f / sum;
        float a[4];
        #pragma unroll
        for (int q = 0; q < 4; ++q) {
            a[q] = e[q] * inv;                       // fp32 a (for asum)
            sm.u.e.at[kg + q][p] = f2bf(a[q] * rr);  // a' = a * rnorm (bf16)
        }
        // asum partial: reduce over the wave's 8 p (lane bits 3..5)
        #pragma unroll
        for (int q = 0; q < 4; ++q) {
            a[q] += __shfl_xor(a[q], 8, 64);
            a[q] += __shfl_xor(a[q], 16, 64);
            a[q] += __shfl_xor(a[q], 32, 64);
        }
        if ((lane >> 3) == 0) {
            #pragma unroll
            for (int q = 0; q < 4; ++q) sm.u.e.asq[wv][kg + q] = a[q];
        }
    }
    __syncthreads();
    if (t < 32)
        asum_p[(n * 32 + pt) * KK + t]
            = sm.u.e.asq[0][t] + sm.u.e.asq[1][t] + sm.u.e.asq[2][t] + sm.u.e.asq[3][t];
    {   // coalesced a' write: k = t>>3, 4 p per thread (8 B)
        const int k = t >> 3, po = (t & 7) * 4;
        ushort4 u;
        u.x = sm.u.e.at[k][po];     u.y = sm.u.e.at[k][po + 1];
        u.z = sm.u.e.at[k][po + 2]; u.w = sm.u.e.at[k][po + 3];
        *(ushort4*)&attn_g[((size_t)n * KK + k) * PP + p0 + po] = u;
    }
}

__global__ __launch_bounds__(256) void k_attn(const void* __restrict__ xv,
                                              const void* __restrict__ wv,
                                              int* __restrict__ flag,
                                              unsigned short* __restrict__ attn_g,
                                              float* __restrict__ asum_p) {
    __shared__ AttnSmem sm;
    __shared__ int s_bad;
    const int t = threadIdx.x;
    if (t == 0) s_bad = 0;
    __syncthreads();
    {   // per-block dtype detect (8KB prefix, L2-broadcast across blocks)
        const unsigned short* xu = (const unsigned short*)xv;
        int bad = 0;
        for (int ii = t; ii < 4096; ii += 256)
            if (((xu[ii] >> 7) & 0xFFu) > 0x9Fu) bad = 1;
        if (bad) atomicOr(&s_bad, 1);
    }
    __syncthreads();
    const int f = s_bad;
    if (blockIdx.x == 0 && t == 0) flag[0] = f;   // for later kernels
    if (f) attn_body<float>((const float*)xv, (const float*)wv, sm, attn_g, asum_p);
    else   attn_body<unsigned short>((const unsigned short*)xv, (const unsigned short*)wv,
                                     sm, attn_g, asum_p);
}

// ---------------------------------------------------------------------------
// K2: vlad GEMM, fragment-direct from global, 8 waves (2k x 2c x 2p halves).
// grid 512 = (n, 32c-tile), block 512.
// ---------------------------------------------------------------------------
struct VladSmem { float asum[32]; float ssq[32]; f32x4 pacc[4][64]; };

template <typename T>
__device__ __forceinline__ void vlad_body(const T* __restrict__ x,
                                          const T* __restrict__ cent, VladSmem& sm,
                                          const unsigned short* __restrict__ attn_g,
                                          const float* __restrict__ asum_p,
                                          float* __restrict__ vlad,
                                          float* __restrict__ ssqnk_p) {
    const int b = blockIdx.x, t = threadIdx.x;
    const int n = b >> 5, ct = b & 31;
    const int lane = t & 63, wvi = t >> 6;
    const int quad = lane >> 4, l15 = lane & 15;
    const int mt = wvi & 1, nt = (wvi >> 1) & 1, ph = wvi >> 2;
    const int krow = mt * 16 + l15;
    const int crow = ct * 32 + nt * 16 + l15;
    if (t < 32) {
        float s = 0.f;
        #pragma unroll
        for (int ps = 0; ps < 32; ++ps) s += asum_p[(n * 32 + ps) * KK + t];
        sm.asum[t] = s;
        sm.ssq[t] = 0.f;
    }
    __syncthreads();
    const unsigned short* apq = attn_g + ((size_t)n * KK + krow) * PP + quad * 8;
    const T* xp = x + (size_t)n * CC * PP + (size_t)crow * PP + quad * 8;
    f32x4 acc = {0.f, 0.f, 0.f, 0.f};
    // depth-4 register pipeline over this wave's 16 p-steps (static slots)
    bf16x8 avq[4], bvq[4];
    #pragma unroll
    for (int ii = 0; ii < 4; ++ii) {
        const int o = (ph * 16 + ii) * 32;
        avq[ii] = *(const bf16x8*)&apq[o];
        bvq[ii] = IO<T>::frag8(&xp[o]);     // bf16: raw 16B; fp32: 2x16B + cvt
    }
    #pragma unroll
    for (int st = 0; st < 16; ++st) {
        const int sl = st & 3;
        acc = __builtin_amdgcn_mfma_f32_16x16x32_bf16(avq[sl], bvq[sl], acc, 0, 0, 0);
        if (st + 4 < 16) {
            const int o = (ph * 16 + st + 4) * 32;
            avq[sl] = *(const bf16x8*)&apq[o];
            bvq[sl] = IO<T>::frag8(&xp[o]);
        }
    }
    // combine p-halves: ph=1 waves publish, ph=0 waves reduce + epilogue
    if (ph == 1) sm.pacc[wvi & 3][lane] = acc;
    __syncthreads();
    if (ph == 0) {
        const f32x4 o = sm.pacc[wvi][lane];
        acc[0] += o[0]; acc[1] += o[1]; acc[2] += o[2]; acc[3] += o[3];
        #pragma unroll
        for (int reg = 0; reg < 4; ++reg) {
            const int kk = mt * 16 + quad * 4 + reg;
            const float A = sm.asum[kk];
            const float v = acc[reg] - A * IO<T>::ld(&cent[kk * CC + crow]);
            vlad[((size_t)n * KK + kk) * CC + crow] = v;
            float sq = v * v;
            sq += __shfl_xor(sq, 1, 64);
            sq += __shfl_xor(sq, 2, 64);
            sq += __shfl_xor(sq, 4, 64);
            sq += __shfl_xor(sq, 8, 64);
            if (l15 == 0) atomicAdd(&sm.ssq[kk], sq);
        }
    }
    __syncthreads();
    if (t < 32) ssqnk_p[(n * 32 + ct) * KK + t] = sm.ssq[t];
}

__global__ __launch_bounds__(512) void k_vlad(const void* __restrict__ xv,
                                              const void* __restrict__ centv,
                                              const int* __restrict__ flag,
                                              const unsigned short* __restrict__ attn_g,
                                              const float* __restrict__ asum_p,
                                              float* __restrict__ vlad,
                                              float* __restrict__ ssqnk_p) {
    __shared__ VladSmem sm;
    if (*flag) vlad_body<float>((const float*)xv, (const float*)centv, sm,
                                attn_g, asum_p, vlad, ssqnk_p);
    else       vlad_body<unsigned short>((const unsigned short*)xv, (const unsigned short*)centv,
                                         sm, attn_g, asum_p, vlad, ssqnk_p);
}

// ---------------------------------------------------------------------------
// K3: factors + scaled output. grid 512 = (n, k), block 256. (Verified.)
// ---------------------------------------------------------------------------
struct OutSmem { float ssq[32]; float rint[32]; float rg; };

template <typename T>
__device__ __forceinline__ void out_body(const float* __restrict__ vlad,
                                         const float* __restrict__ ssqnk_p,
                                         OutSmem& sm, T* __restrict__ out) {
    const int b = blockIdx.x, t = threadIdx.x;
    const int n = b >> 5, k = b & 31;
    if (t < 32) {
        float s = 0.f;
        #pragma unroll
        for (int ct = 0; ct < 32; ++ct) s += ssqnk_p[(n * 32 + ct) * KK + t];
        sm.ssq[t] = s;
    }
    __syncthreads();
    if (t < 64) {
        const float s = (t < 32) ? sm.ssq[t] : 0.f;
        const float rr = 1.0f / fmaxf(sqrtf(s), EPSF);
        float gg = s * rr * rr;
        #pragma unroll
        for (int off = 32; off > 0; off >>= 1) gg += __shfl_down(gg, off, 64);
        if (t == 0) sm.rg = 1.0f / fmaxf(sqrtf(gg), EPSF);
        if (t < 32) sm.rint[t] = rr;
    }
    __syncthreads();
    const float f = sm.rint[k] * sm.rg;
    const size_t ob = ((size_t)n * KK + k) * CC + 4 * t;
    f32x4 v = *(const f32x4*)&vlad[ob];
    v[0] *= f; v[1] *= f; v[2] *= f; v[3] *= f;
    IO<T>::st4(&out[ob], v);
}

__global__ __launch_bounds__(256) void k_out(const float* __restrict__ vlad,
                                             const float* __restrict__ ssqnk_p,
                                             const int* __restrict__ flag,
                                             void* __restrict__ outv) {
    __shared__ OutSmem sm;
    if (*flag) out_body<float>(vlad, ssqnk_p, sm, (float*)outv);
    else       out_body<unsigned short>(vlad, ssqnk_p, sm, (unsigned short*)outv);
}

extern "C" void kernel_launch(void* const* d_in, const int* in_sizes, int n_in,
                              void* d_out, int out_size, void* d_ws, size_t ws_size,
                              hipStream_t stream) {
    const void* x    = d_in[0];
    const void* w    = d_in[1];
    const void* cent = d_in[2];

    float* ws      = (float*)d_ws;
    float* asum_p  = ws;                                    // NB*32*KK = 16384 fl
    float* ssqnk_p = asum_p + NB * 32 * KK;                 // NB*32*KK = 16384 fl
    float* vlad    = ssqnk_p + NB * 32 * KK;                // NB*KK*CC = 524288 fl
    int*   flag    = (int*)(vlad + (size_t)NB * KK * CC);   // 4 ints
    unsigned short* attn_g = (unsigned short*)(flag + 4);   // NB*KK*PP sh (1MB)

    k_attn<<<NB * 32, 256, 0, stream>>>(x, w, flag, attn_g, asum_p);
    k_vlad<<<NB * 32, 512, 0, stream>>>(x, cent, flag, attn_g, asum_p, vlad, ssqnk_p);
    k_out<<<NB * KK, 256, 0, stream>>>(vlad, ssqnk_p, flag, d_out);
}